// Round 3
// baseline (320.572 us; speedup 1.0000x reference)
//
#include <hip/hip_runtime.h>
#include <hip/hip_bf16.h>

#define N_NODES 50000
#define N_EDGES 600000
#define D 128
#define BM 32

typedef __bf16 bf16x8 __attribute__((ext_vector_type(8)));
typedef float f32x4 __attribute__((ext_vector_type(4)));

__device__ __forceinline__ float bits2f(unsigned int u) {
    union { unsigned int i; float f; } t; t.i = u; return t.f;
}
__device__ __forceinline__ unsigned short f2bf(float x) {
    unsigned int u = __builtin_bit_cast(unsigned int, x);
    unsigned int r = (u + 0x7fff + ((u >> 16) & 1)) >> 16;
    return (unsigned short)r;
}

// ---------------------------------------------------------------------------
// prep: fused {cvt_feat | hist | cvt_w} via blockIdx range partition
//   cvt_feat blocks: [0, 6250)        1.6M threads x 4 floats
//   hist blocks:     [6250, 8594)     600K threads
//   cvt_w blocks:    [8594, 8978)     98304 threads
// ---------------------------------------------------------------------------
#define PREP_CVT_BLOCKS 6250
#define PREP_HIST_BLOCKS 2344
#define PREP_W_BLOCKS 384
__global__ void prep_kernel(const float* __restrict__ feat, unsigned short* __restrict__ g_bf,
                            const int* __restrict__ dst, int* __restrict__ deg,
                            const float* w0, const float* w1, const float* w2,
                            const float* w3, const float* w4, const float* w5,
                            unsigned short* __restrict__ WT) {
    int b = blockIdx.x;
    if (b < PREP_CVT_BLOCKS) {
        int i = b * 256 + threadIdx.x;
        if (i < N_NODES * D / 4) {
            float4 v = *(const float4*)(feat + (size_t)i * 4);
            ushort4 o;
            o.x = f2bf(v.x); o.y = f2bf(v.y); o.z = f2bf(v.z); o.w = f2bf(v.w);
            *(ushort4*)(g_bf + (size_t)i * 4) = o;
        }
    } else if (b < PREP_CVT_BLOCKS + PREP_HIST_BLOCKS) {
        int i = (b - PREP_CVT_BLOCKS) * 256 + threadIdx.x;
        if (i < N_EDGES) atomicAdd(&deg[dst[i]], 1);
    } else {
        int j = (b - PREP_CVT_BLOCKS - PREP_HIST_BLOCKS) * 256 + threadIdx.x; // 0..98303
        int m = j >> 14;               // which of 6 matrices
        int e = j & 16383;
        const float* src = m == 0 ? w0 : m == 1 ? w1 : m == 2 ? w2 : m == 3 ? w3 : m == 4 ? w4 : w5;
        int n = e >> 7, k = e & 127;
        WT[m * 16384 + n * 128 + k] = f2bf(src[k * 128 + n]);
    }
}

// ---------------------------------------------------------------------------
// scan (3-stage hierarchical)
// ---------------------------------------------------------------------------
__global__ void scan1_kernel(const int* __restrict__ deg, int* __restrict__ partial,
                             int* __restrict__ blk_sums) {
    __shared__ int ws[16];
    int i = blockIdx.x * 1024 + threadIdx.x;
    int x = (i < N_NODES) ? deg[i] : 0;
    int lane = threadIdx.x & 63, wid = threadIdx.x >> 6;
    int v = x;
    #pragma unroll
    for (int off = 1; off < 64; off <<= 1) {
        int t = __shfl_up(v, off);
        if (lane >= off) v += t;
    }
    if (lane == 63) ws[wid] = v;
    __syncthreads();
    if (threadIdx.x == 0) {
        int c = 0;
        #pragma unroll
        for (int j = 0; j < 16; ++j) { int t = ws[j]; ws[j] = c; c += t; }
        blk_sums[blockIdx.x] = c;
    }
    __syncthreads();
    if (i < N_NODES) partial[i] = v - x + ws[wid];
}

__global__ void scan2_kernel(int* __restrict__ blk_sums, int nb) {
    int lane = threadIdx.x;
    int v = (lane < nb) ? blk_sums[lane] : 0;
    int x = v;
    #pragma unroll
    for (int off = 1; off < 64; off <<= 1) {
        int t = __shfl_up(v, off);
        if (lane >= off) v += t;
    }
    if (lane < nb) blk_sums[lane] = v - x;
}

__global__ void scan3_kernel(const int* __restrict__ partial, const int* __restrict__ blk_sums,
                             const int* __restrict__ deg, int* __restrict__ row_start,
                             int* __restrict__ cursor, float* __restrict__ deg_inv) {
    int i = blockIdx.x * 256 + threadIdx.x;
    if (i < N_NODES) {
        int rs = partial[i] + blk_sums[i >> 10];
        row_start[i] = rs;
        cursor[i] = rs;
        deg_inv[i] = 1.0f / fmaxf((float)deg[i], 1.0f);
    }
    if (i == 0) row_start[N_NODES] = N_EDGES;
}

__global__ void fill_kernel(const int* __restrict__ src, const int* __restrict__ dst,
                            int* __restrict__ cursor, int* __restrict__ esrc, int n) {
    int i = blockIdx.x * blockDim.x + threadIdx.x;
    if (i < n) {
        int p = atomicAdd(&cursor[dst[i]], 1);
        esrc[p] = src[i];
    }
}

// ---------------------------------------------------------------------------
// Fused layer: out = relu?( h @ Ws + (deg_inv * A.h) @ Wn + b )
// BM=32 rows/block, 256 threads (4 waves).
//  - B fragments (both phases) preloaded from global into 64 VGPRs
//  - h tile staged to swizzled LDS (8KB)
//  - msum gathered by 16 lane-groups directly into swizzled LDS (8KB)
//  - one barrier, 8 k-steps of mfma_16x16x32_bf16, bias+relu epilogue
// ---------------------------------------------------------------------------
__device__ __forceinline__ void acc_add(float* a, uint4 v) {
    unsigned int w[4] = {v.x, v.y, v.z, v.w};
    #pragma unroll
    for (int j = 0; j < 4; ++j) {
        a[2*j]   += bits2f(w[j] << 16);
        a[2*j+1] += bits2f(w[j] & 0xffff0000u);
    }
}

__global__ __launch_bounds__(256) void layer_kernel(
        const unsigned short* __restrict__ h, const int* __restrict__ row_start,
        const int* __restrict__ esrc, const float* __restrict__ deg_inv,
        const unsigned short* __restrict__ WsT, const unsigned short* __restrict__ WnT,
        const float* __restrict__ bias, void* __restrict__ outp,
        int do_relu, int store_f32) {
    __shared__ char lds[BM * 256 * 2];
    char* Ah = lds;                 // phase0 A: h tile   [32][128] bf16, swizzled
    char* Am = lds + BM * 256;      // phase1 A: msum     [32][128] bf16, swizzled
    int tid = threadIdx.x;
    int l = tid & 63, w = tid >> 6;
    int row0 = blockIdx.x * BM;

    // ---- preload B fragments for both phases (L2-broadcast) ----
    bf16x8 bfrag[2][2][4];   // [phase][nt][ks]
    {
        size_t off = (size_t)(w * 32 + (l & 15)) * D + ((l >> 4) * 8);
        const unsigned short* Wp0 = WsT + off;
        const unsigned short* Wp1 = WnT + off;
        #pragma unroll
        for (int nt = 0; nt < 2; ++nt)
            #pragma unroll
            for (int ks = 0; ks < 4; ++ks) {
                bfrag[0][nt][ks] = *(const bf16x8*)(Wp0 + nt * 16 * D + ks * 32);
                bfrag[1][nt][ks] = *(const bf16x8*)(Wp1 + nt * 16 * D + ks * 32);
            }
    }

    // ---- stage h tile: 512 x 16B chunks, 2 per thread ----
    #pragma unroll
    for (int i = 0; i < 2; ++i) {
        int c = tid + i * 256;
        int r = c >> 4, ch = c & 15;
        int gr = row0 + r; if (gr >= N_NODES) gr = N_NODES - 1;
        uint4 v = *(const uint4*)(h + (size_t)gr * D + ch * 8);
        *(uint4*)(Ah + r * 256 + ((ch << 4) ^ ((r & 7) << 4))) = v;
    }

    // ---- gather msum: 16 groups x 16 lanes, 2 nodes per group ----
    {
        int gi = tid >> 4, l16 = tid & 15;
        const unsigned short* hl = h + l16 * 8;
        #pragma unroll
        for (int nn = 0; nn < 2; ++nn) {
            int r = gi * 2 + nn;
            int node = row0 + r;
            float acc[8] = {0, 0, 0, 0, 0, 0, 0, 0};
            float di = 0.f;
            if (node < N_NODES) {
                int s = row_start[node], e = row_start[node + 1];
                int k = s;
                for (; k + 4 <= e; k += 4) {
                    int i0 = esrc[k], i1 = esrc[k + 1], i2 = esrc[k + 2], i3 = esrc[k + 3];
                    uint4 v0 = *(const uint4*)(hl + (size_t)i0 * D);
                    uint4 v1 = *(const uint4*)(hl + (size_t)i1 * D);
                    uint4 v2 = *(const uint4*)(hl + (size_t)i2 * D);
                    uint4 v3 = *(const uint4*)(hl + (size_t)i3 * D);
                    acc_add(acc, v0); acc_add(acc, v1); acc_add(acc, v2); acc_add(acc, v3);
                }
                for (; k < e; ++k) {
                    uint4 v = *(const uint4*)(hl + (size_t)esrc[k] * D);
                    acc_add(acc, v);
                }
                di = deg_inv[node];
            }
            unsigned short o[8];
            #pragma unroll
            for (int j = 0; j < 8; ++j) o[j] = f2bf(acc[j] * di);
            *(uint4*)(Am + r * 256 + ((l16 << 4) ^ ((r & 7) << 4))) = *(uint4*)o;
        }
    }
    __syncthreads();

    // ---- MFMA: 2 phases x 4 ks x (2 mt x 2 nt) ----
    f32x4 acc[2][2];
    #pragma unroll
    for (int mt = 0; mt < 2; ++mt)
        #pragma unroll
        for (int nt = 0; nt < 2; ++nt)
            acc[mt][nt] = (f32x4)0.0f;

    #pragma unroll
    for (int ph = 0; ph < 2; ++ph) {
        char* Ab = ph ? Am : Ah;
        #pragma unroll
        for (int ks = 0; ks < 4; ++ks) {
            int kb = ks * 64 + ((l >> 4) << 4);
            bf16x8 a[2];
            #pragma unroll
            for (int mt = 0; mt < 2; ++mt) {
                int r = mt * 16 + (l & 15);
                a[mt] = *(const bf16x8*)(Ab + r * 256 + (kb ^ ((r & 7) << 4)));
            }
            #pragma unroll
            for (int mt = 0; mt < 2; ++mt)
                #pragma unroll
                for (int nt = 0; nt < 2; ++nt)
                    acc[mt][nt] = __builtin_amdgcn_mfma_f32_16x16x32_bf16(a[mt], bfrag[ph][nt][ks], acc[mt][nt], 0, 0, 0);
        }
    }

    // ---- epilogue ----
    #pragma unroll
    for (int nt = 0; nt < 2; ++nt) {
        int col = w * 32 + nt * 16 + (l & 15);
        float bv = bias[col];
        #pragma unroll
        for (int mt = 0; mt < 2; ++mt) {
            #pragma unroll
            for (int r = 0; r < 4; ++r) {
                int grow = row0 + mt * 16 + ((l >> 4) << 2) + r;
                if (grow < N_NODES) {
                    float v = acc[mt][nt][r] + bv;
                    if (do_relu) v = fmaxf(v, 0.f);
                    if (store_f32) ((float*)outp)[(size_t)grow * D + col] = v;
                    else ((unsigned short*)outp)[(size_t)grow * D + col] = f2bf(v);
                }
            }
        }
    }
}

// ---------------------------------------------------------------------------
// Launch
// ---------------------------------------------------------------------------
static inline size_t align_up(size_t x, size_t a) { return (x + a - 1) & ~(a - 1); }

extern "C" void kernel_launch(void* const* d_in, const int* in_sizes, int n_in,
                              void* d_out, int out_size, void* d_ws, size_t ws_size,
                              hipStream_t stream) {
    const float* g_feat = (const float*)d_in[0];
    const int* src = (const int*)d_in[1];
    const int* dst = (const int*)d_in[2];
    const float* Ws1 = (const float*)d_in[3];
    const float* Wn1 = (const float*)d_in[4];
    const float* b1  = (const float*)d_in[5];
    const float* Ws2 = (const float*)d_in[6];
    const float* Wn2 = (const float*)d_in[7];
    const float* b2  = (const float*)d_in[8];
    const float* Ws3 = (const float*)d_in[9];
    const float* Wn3 = (const float*)d_in[10];
    const float* b3  = (const float*)d_in[11];
    float* out = (float*)d_out;

    char* ws = (char*)d_ws;
    int* deg        = (int*)ws;            ws += align_up(N_NODES * 4, 256);
    int* row_start  = (int*)ws;            ws += align_up((N_NODES + 1) * 4, 256);
    int* cursor     = (int*)ws;            ws += align_up(N_NODES * 4, 256);
    float* deg_inv  = (float*)ws;          ws += align_up(N_NODES * 4, 256);
    int* partial    = (int*)ws;            ws += align_up(N_NODES * 4, 256);
    int* blk_sums   = (int*)ws;            ws += align_up(64 * 4, 256);
    int* esrc       = (int*)ws;            ws += align_up(N_EDGES * 4, 256);
    unsigned short* g_bf = (unsigned short*)ws;  ws += align_up((size_t)N_NODES * D * 2, 256);
    unsigned short* WT   = (unsigned short*)ws;  ws += align_up(6 * 128 * 128 * 2, 256);
    unsigned short* bufA = (unsigned short*)ws;  ws += align_up((size_t)N_NODES * D * 2, 256);
    unsigned short* bufB = (unsigned short*)ws;  ws += align_up((size_t)N_NODES * D * 2, 256);

    hipMemsetAsync(deg, 0, N_NODES * 4, stream);
    prep_kernel<<<PREP_CVT_BLOCKS + PREP_HIST_BLOCKS + PREP_W_BLOCKS, 256, 0, stream>>>(
        g_feat, g_bf, dst, deg, Ws1, Wn1, Ws2, Wn2, Ws3, Wn3, WT);
    int nb = (N_NODES + 1023) / 1024;
    scan1_kernel<<<nb, 1024, 0, stream>>>(deg, partial, blk_sums);
    scan2_kernel<<<1, 64, 0, stream>>>(blk_sums, nb);
    scan3_kernel<<<(N_NODES + 255) / 256, 256, 0, stream>>>(partial, blk_sums, deg, row_start, cursor, deg_inv);
    fill_kernel<<<(N_EDGES + 255) / 256, 256, 0, stream>>>(src, dst, cursor, esrc, N_EDGES);

    dim3 grid((N_NODES + BM - 1) / BM);
    const unsigned short *WsT1 = WT, *WnT1 = WT + 16384, *WsT2 = WT + 2*16384,
                         *WnT2 = WT + 3*16384, *WsT3 = WT + 4*16384, *WnT3 = WT + 5*16384;

    layer_kernel<<<grid, 256, 0, stream>>>(g_bf, row_start, esrc, deg_inv, WsT1, WnT1, b1, bufA, 1, 0);
    layer_kernel<<<grid, 256, 0, stream>>>(bufA, row_start, esrc, deg_inv, WsT2, WnT2, b2, bufB, 1, 0);
    layer_kernel<<<grid, 256, 0, stream>>>(bufB, row_start, esrc, deg_inv, WsT3, WnT3, b3, out, 0, 1);
}